// Round 5
// baseline (2014.257 us; speedup 1.0000x reference)
//
#include <hip/hip_runtime.h>

#define NUM_USERS 100000
#define NUM_ITEMS 50000
#define NUM_EDGES 4000000
#define DIM 64

// Source-table slicing: 1<<14 = 16384 rows/slice = 2 MB bf16 -> fits per-XCD
// 4 MB L2. Gather runs one launch per source slice so concurrent waves all
// read the same 2 MB window (L2-resident), instead of randomly hitting the
// whole 12.8 MB table (L2-thrash -> Infinity-Cache random-granule wall).
#define SLICE_SHIFT 14
#define SLICES_U ((NUM_USERS + (1 << SLICE_SHIFT) - 1) >> SLICE_SHIFT)  // 7
#define SLICES_I ((NUM_ITEMS + (1 << SLICE_SHIFT) - 1) >> SLICE_SHIFT)  // 4

// ---------------- fallback: scatter-atomic (round-1 kernel) ----------------
__global__ __launch_bounds__(256) void lightgcn_scatter(
    const float* __restrict__ user_emb,
    const float* __restrict__ item_emb,
    const float* __restrict__ edge_norm,
    const int* __restrict__ u_idx,
    const int* __restrict__ i_idx,
    float* __restrict__ agg_users,
    float* __restrict__ agg_items)
{
    long long gid = (long long)blockIdx.x * blockDim.x + threadIdx.x;
    int edge = (int)(gid >> 6);
    int lane = (int)(gid & 63);
    if (edge >= NUM_EDGES) return;
    int u = u_idx[edge];
    int i = i_idx[edge];
    float n = edge_norm[edge];
    float uval = user_emb[(size_t)u * DIM + lane];
    float ival = item_emb[(size_t)i * DIM + lane];
    atomicAdd(&agg_items[(size_t)i * DIM + lane], n * uval);
    atomicAdd(&agg_users[(size_t)u * DIM + lane], n * ival);
}

// ---------------- bf16 conversion of embedding tables ----------------
__global__ __launch_bounds__(256) void convert_bf16(
    const float4* __restrict__ src, ushort* __restrict__ dst, int n4)
{
    int t = blockIdx.x * blockDim.x + threadIdx.x;
    if (t >= n4) return;
    float4 v = src[t];
    ushort4 o;
    uint b;
    b = __float_as_uint(v.x); o.x = (ushort)((b + 0x7FFFu + ((b >> 16) & 1u)) >> 16);
    b = __float_as_uint(v.y); o.y = (ushort)((b + 0x7FFFu + ((b >> 16) & 1u)) >> 16);
    b = __float_as_uint(v.z); o.z = (ushort)((b + 0x7FFFu + ((b >> 16) & 1u)) >> 16);
    b = __float_as_uint(v.w); o.w = (ushort)((b + 0x7FFFu + ((b >> 16) & 1u)) >> 16);
    ((ushort4*)dst)[t] = o;
}

// ---------------- CSR build (bins keyed by (src_slice, dst_row)) -----------
__global__ __launch_bounds__(256) void edge_hist(
    const int4* __restrict__ u4, const int4* __restrict__ i4,
    int* __restrict__ u_cnt, int* __restrict__ i_cnt,
    int su_shift, int si_shift)
{
    int t = blockIdx.x * blockDim.x + threadIdx.x;
    if (t >= NUM_EDGES / 4) return;
    int4 u = u4[t];
    int4 i = i4[t];
    atomicAdd(&i_cnt[(u.x >> su_shift) * NUM_ITEMS + i.x], 1);
    atomicAdd(&i_cnt[(u.y >> su_shift) * NUM_ITEMS + i.y], 1);
    atomicAdd(&i_cnt[(u.z >> su_shift) * NUM_ITEMS + i.z], 1);
    atomicAdd(&i_cnt[(u.w >> su_shift) * NUM_ITEMS + i.w], 1);
    atomicAdd(&u_cnt[(i.x >> si_shift) * NUM_USERS + u.x], 1);
    atomicAdd(&u_cnt[(i.y >> si_shift) * NUM_USERS + u.y], 1);
    atomicAdd(&u_cnt[(i.z >> si_shift) * NUM_USERS + u.z], 1);
    atomicAdd(&u_cnt[(i.w >> si_shift) * NUM_USERS + u.w], 1);
}

// grid=2: block 0 scans item bins (n_i), block 1 scans user bins (n_u).
__global__ __launch_bounds__(1024) void scan_offsets(
    int* __restrict__ i_off, int* __restrict__ i_cur, int n_i,
    int* __restrict__ u_off, int* __restrict__ u_cur, int n_u)
{
    int* cnt; int* cur; int n;
    if (blockIdx.x == 0) { cnt = i_off; cur = i_cur; n = n_i; }
    else                 { cnt = u_off; cur = u_cur; n = n_u; }
    const int t = threadIdx.x;
    const int chunk = (n + 1023) / 1024;
    const int base = t * chunk;
    const int lim  = (base + chunk < n) ? base + chunk : n;

    int local = 0;
    for (int i = base; i < lim; ++i) local += cnt[i];

    __shared__ int s[1024];
    s[t] = local;
    __syncthreads();
    for (int off = 1; off < 1024; off <<= 1) {
        int v = (t >= off) ? s[t - off] : 0;
        __syncthreads();
        s[t] += v;
        __syncthreads();
    }
    int running = (t == 0) ? 0 : s[t - 1];
    if (t == 1023) cnt[n] = s[1023];
    for (int i = base; i < lim; ++i) {
        int c = cnt[i];
        cnt[i] = running;
        cur[i] = running;
        running += c;
    }
}

// Placement: 4 separate 4B scattered stores per edge (empirically ~2x faster
// than packed int2 8B stores on gfx950 — round-3 regression evidence).
__global__ __launch_bounds__(256) void edge_place(
    const int* __restrict__ u_idx, const int* __restrict__ i_idx,
    const float* __restrict__ edge_norm,
    int* __restrict__ i_cur, int* __restrict__ u_cur,
    int* __restrict__ ci_src, float* __restrict__ ci_w,
    int* __restrict__ cu_src, float* __restrict__ cu_w,
    int su_shift, int si_shift)
{
    int e = blockIdx.x * blockDim.x + threadIdx.x;
    if (e >= NUM_EDGES) return;
    int u = u_idx[e];
    int i = i_idx[e];
    float w = edge_norm[e];
    int pi = atomicAdd(&i_cur[(u >> su_shift) * NUM_ITEMS + i], 1);
    ci_src[pi] = u;  ci_w[pi] = w;
    int pu = atomicAdd(&u_cur[(i >> si_shift) * NUM_USERS + u], 1);
    cu_src[pu] = i;  cu_w[pu] = w;
}

// ---------------- gather pass: one 64-lane wave per dst row, one src slice --
__global__ __launch_bounds__(256) void gather_pass(
    const int* __restrict__ off, int bin_base,
    const int* __restrict__ src, const float* __restrict__ w,
    const ushort* __restrict__ emb16,
    float* __restrict__ out, int nrows, int accumulate)
{
    int gid  = blockIdx.x * blockDim.x + threadIdx.x;
    int row  = gid >> 6;
    int lane = gid & 63;
    if (row >= nrows) return;
    int b = bin_base + row;
    int s = off[b];
    int e = off[b + 1];
    float acc = accumulate ? out[(size_t)row * DIM + lane] : 0.f;
    int k = s;
    for (; k + 8 <= e; k += 8) {
        int   s0 = src[k],   s1 = src[k+1], s2 = src[k+2], s3 = src[k+3];
        int   s4 = src[k+4], s5 = src[k+5], s6 = src[k+6], s7 = src[k+7];
        float w0 = w[k],   w1 = w[k+1], w2 = w[k+2], w3 = w[k+3];
        float w4 = w[k+4], w5 = w[k+5], w6 = w[k+6], w7 = w[k+7];
        ushort b0 = emb16[(size_t)s0 * DIM + lane];
        ushort b1 = emb16[(size_t)s1 * DIM + lane];
        ushort b2 = emb16[(size_t)s2 * DIM + lane];
        ushort b3 = emb16[(size_t)s3 * DIM + lane];
        ushort b4 = emb16[(size_t)s4 * DIM + lane];
        ushort b5 = emb16[(size_t)s5 * DIM + lane];
        ushort b6 = emb16[(size_t)s6 * DIM + lane];
        ushort b7 = emb16[(size_t)s7 * DIM + lane];
        acc += w0 * __uint_as_float((uint)b0 << 16);
        acc += w1 * __uint_as_float((uint)b1 << 16);
        acc += w2 * __uint_as_float((uint)b2 << 16);
        acc += w3 * __uint_as_float((uint)b3 << 16);
        acc += w4 * __uint_as_float((uint)b4 << 16);
        acc += w5 * __uint_as_float((uint)b5 << 16);
        acc += w6 * __uint_as_float((uint)b6 << 16);
        acc += w7 * __uint_as_float((uint)b7 << 16);
    }
    for (; k + 4 <= e; k += 4) {
        int   s0 = src[k],   s1 = src[k+1], s2 = src[k+2], s3 = src[k+3];
        float w0 = w[k],   w1 = w[k+1], w2 = w[k+2], w3 = w[k+3];
        ushort b0 = emb16[(size_t)s0 * DIM + lane];
        ushort b1 = emb16[(size_t)s1 * DIM + lane];
        ushort b2 = emb16[(size_t)s2 * DIM + lane];
        ushort b3 = emb16[(size_t)s3 * DIM + lane];
        acc += w0 * __uint_as_float((uint)b0 << 16);
        acc += w1 * __uint_as_float((uint)b1 << 16);
        acc += w2 * __uint_as_float((uint)b2 << 16);
        acc += w3 * __uint_as_float((uint)b3 << 16);
    }
    for (; k < e; ++k) {
        ushort b0 = emb16[(size_t)src[k] * DIM + lane];
        acc += w[k] * __uint_as_float((uint)b0 << 16);
    }
    out[(size_t)row * DIM + lane] = acc;
}

extern "C" void kernel_launch(void* const* d_in, const int* in_sizes, int n_in,
                              void* d_out, int out_size, void* d_ws, size_t ws_size,
                              hipStream_t stream) {
    const float* user_emb  = (const float*)d_in[0];
    const float* item_emb  = (const float*)d_in[1];
    const float* edge_norm = (const float*)d_in[2];
    const int*   u_idx     = (const int*)d_in[3];
    const int*   i_idx     = (const int*)d_in[4];

    float* agg_users = (float*)d_out;                        // 100000*64
    float* agg_items = agg_users + (size_t)NUM_USERS * DIM;  // 50000*64

    const size_t csr_bytes  = (size_t)NUM_EDGES * 2 * (sizeof(int) + sizeof(float));
    const size_t bf16_bytes = ((size_t)NUM_USERS + NUM_ITEMS) * DIM * sizeof(ushort);
    auto need_for = [&](int SU, int SI) -> size_t {
        size_t off_bytes = ((size_t)SU * NUM_ITEMS + 1 + (size_t)SI * NUM_USERS + 1
                          + (size_t)SU * NUM_ITEMS + (size_t)SI * NUM_USERS)
                          * sizeof(int);
        return off_bytes + 64 + csr_bytes + 64 + bf16_bytes;
    };

    int SU, SI, su_shift, si_shift;
    if (ws_size >= need_for(SLICES_U, SLICES_I)) {
        SU = SLICES_U; SI = SLICES_I;
        su_shift = SLICE_SHIFT; si_shift = SLICE_SHIFT;
    } else if (ws_size >= need_for(1, 1)) {
        SU = 1; SI = 1;
        su_shift = 17; si_shift = 17;   // 2^17 > both table sizes -> slice 0
    } else {
        // lowest tier: scatter-atomic
        hipMemsetAsync(d_out, 0, (size_t)out_size * sizeof(float), stream);
        const long long total_threads = (long long)NUM_EDGES * 64;
        const int blocks = (int)((total_threads + 255) / 256);
        lightgcn_scatter<<<blocks, 256, 0, stream>>>(
            user_emb, item_emb, edge_norm, u_idx, i_idx, agg_users, agg_items);
        return;
    }

    const int n_i = SU * NUM_ITEMS;   // item-CSR bin count
    const int n_u = SI * NUM_USERS;   // user-CSR bin count

    char* p = (char*)d_ws;
    int*   i_off  = (int*)p;   p += (size_t)(n_i + 1) * sizeof(int);
    int*   u_off  = (int*)p;   p += (size_t)(n_u + 1) * sizeof(int);
    int*   i_cur  = (int*)p;   p += (size_t)n_i * sizeof(int);
    int*   u_cur  = (int*)p;   p += (size_t)n_u * sizeof(int);
    p = (char*)(((uintptr_t)p + 63) & ~(uintptr_t)63);
    int*   ci_src = (int*)p;   p += (size_t)NUM_EDGES * sizeof(int);
    float* ci_w   = (float*)p; p += (size_t)NUM_EDGES * sizeof(float);
    int*   cu_src = (int*)p;   p += (size_t)NUM_EDGES * sizeof(int);
    float* cu_w   = (float*)p; p += (size_t)NUM_EDGES * sizeof(float);
    p = (char*)(((uintptr_t)p + 63) & ~(uintptr_t)63);
    ushort* ue16  = (ushort*)p; p += (size_t)NUM_USERS * DIM * sizeof(ushort);
    ushort* ie16  = (ushort*)p;

    // zero bins+cursors (contiguous)
    hipMemsetAsync(i_off, 0,
                   (size_t)(n_i + 1 + n_u + 1 + n_i + n_u) * sizeof(int), stream);

    const int un4 = NUM_USERS * DIM / 4;
    const int in4 = NUM_ITEMS * DIM / 4;
    convert_bf16<<<(un4 + 255) / 256, 256, 0, stream>>>(
        (const float4*)user_emb, ue16, un4);
    convert_bf16<<<(in4 + 255) / 256, 256, 0, stream>>>(
        (const float4*)item_emb, ie16, in4);

    edge_hist<<<(NUM_EDGES / 4 + 255) / 256, 256, 0, stream>>>(
        (const int4*)u_idx, (const int4*)i_idx, u_off, i_off, su_shift, si_shift);
    scan_offsets<<<2, 1024, 0, stream>>>(i_off, i_cur, n_i, u_off, u_cur, n_u);
    edge_place<<<(NUM_EDGES + 255) / 256, 256, 0, stream>>>(
        u_idx, i_idx, edge_norm, i_cur, u_cur,
        ci_src, ci_w, cu_src, cu_w, su_shift, si_shift);

    // agg_items: gather user rows, one launch per user-table slice
    for (int s = 0; s < SU; ++s) {
        gather_pass<<<((NUM_ITEMS * 64) + 255) / 256, 256, 0, stream>>>(
            i_off, s * NUM_ITEMS, ci_src, ci_w, ue16, agg_items, NUM_ITEMS,
            s > 0 ? 1 : 0);
    }
    // agg_users: gather item rows, one launch per item-table slice
    for (int s = 0; s < SI; ++s) {
        gather_pass<<<((NUM_USERS * 64) + 255) / 256, 256, 0, stream>>>(
            u_off, s * NUM_USERS, cu_src, cu_w, ie16, agg_users, NUM_USERS,
            s > 0 ? 1 : 0);
    }
}

// Round 6
// 1130.636 us; speedup vs baseline: 1.7815x; 1.7815x over previous
//
#include <hip/hip_runtime.h>

#define NUM_USERS 100000
#define NUM_ITEMS 50000
#define NUM_EDGES 4000000
#define DIM 64

// Source-table slicing: 1<<14 = 16384 rows/slice = 2 MB bf16 per slice.
#define SLICE_SHIFT 14
#define SLICES_U ((NUM_USERS + (1 << SLICE_SHIFT) - 1) >> SLICE_SHIFT)  // 7
#define SLICES_I ((NUM_ITEMS + (1 << SLICE_SHIFT) - 1) >> SLICE_SHIFT)  // 4

#define SCAN_NB 512        // blocks in multi-block scan
#define SCAN_THREADS 256

// ---------------- fallback: scatter-atomic (round-1 kernel) ----------------
__global__ __launch_bounds__(256) void lightgcn_scatter(
    const float* __restrict__ user_emb,
    const float* __restrict__ item_emb,
    const float* __restrict__ edge_norm,
    const int* __restrict__ u_idx,
    const int* __restrict__ i_idx,
    float* __restrict__ agg_users,
    float* __restrict__ agg_items)
{
    long long gid = (long long)blockIdx.x * blockDim.x + threadIdx.x;
    int edge = (int)(gid >> 6);
    int lane = (int)(gid & 63);
    if (edge >= NUM_EDGES) return;
    int u = u_idx[edge];
    int i = i_idx[edge];
    float n = edge_norm[edge];
    float uval = user_emb[(size_t)u * DIM + lane];
    float ival = item_emb[(size_t)i * DIM + lane];
    atomicAdd(&agg_items[(size_t)i * DIM + lane], n * uval);
    atomicAdd(&agg_users[(size_t)u * DIM + lane], n * ival);
}

// ---------------- bf16 conversion of embedding tables ----------------
__global__ __launch_bounds__(256) void convert_bf16(
    const float4* __restrict__ src, ushort* __restrict__ dst, int n4)
{
    int t = blockIdx.x * blockDim.x + threadIdx.x;
    if (t >= n4) return;
    float4 v = src[t];
    ushort4 o;
    uint b;
    b = __float_as_uint(v.x); o.x = (ushort)((b + 0x7FFFu + ((b >> 16) & 1u)) >> 16);
    b = __float_as_uint(v.y); o.y = (ushort)((b + 0x7FFFu + ((b >> 16) & 1u)) >> 16);
    b = __float_as_uint(v.z); o.z = (ushort)((b + 0x7FFFu + ((b >> 16) & 1u)) >> 16);
    b = __float_as_uint(v.w); o.w = (ushort)((b + 0x7FFFu + ((b >> 16) & 1u)) >> 16);
    ((ushort4*)dst)[t] = o;
}

// ---------------- CSR build (concatenated bins) ----------------------------
// item bins: [0, n_i) keyed (u_slice, i);  user bins: [n_i, n_i+n_u) keyed
// (i_slice, u). One scan serves both; u-offsets land in [NUM_EDGES, 2*NUM_EDGES).
__global__ __launch_bounds__(256) void edge_hist(
    const int4* __restrict__ u4, const int4* __restrict__ i4,
    int* __restrict__ cnt, int n_i, int su_shift, int si_shift)
{
    int t = blockIdx.x * blockDim.x + threadIdx.x;
    if (t >= NUM_EDGES / 4) return;
    int4 u = u4[t];
    int4 i = i4[t];
    atomicAdd(&cnt[(u.x >> su_shift) * NUM_ITEMS + i.x], 1);
    atomicAdd(&cnt[(u.y >> su_shift) * NUM_ITEMS + i.y], 1);
    atomicAdd(&cnt[(u.z >> su_shift) * NUM_ITEMS + i.z], 1);
    atomicAdd(&cnt[(u.w >> su_shift) * NUM_ITEMS + i.w], 1);
    atomicAdd(&cnt[n_i + (i.x >> si_shift) * NUM_USERS + u.x], 1);
    atomicAdd(&cnt[n_i + (i.y >> si_shift) * NUM_USERS + u.y], 1);
    atomicAdd(&cnt[n_i + (i.z >> si_shift) * NUM_USERS + u.z], 1);
    atomicAdd(&cnt[n_i + (i.w >> si_shift) * NUM_USERS + u.w], 1);
}

// ---------------- 3-phase multi-block exclusive scan ----------------------
__global__ __launch_bounds__(SCAN_THREADS) void scan_block_sums(
    const int* __restrict__ cnt, int* __restrict__ bsum, int n, int chunk)
{
    int b = blockIdx.x, t = threadIdx.x;
    int base = b * chunk;
    int end  = base + chunk < n ? base + chunk : n;
    int tch  = (chunk + SCAN_THREADS - 1) / SCAN_THREADS;
    int s = base + t * tch;
    int e = s + tch < end ? s + tch : end;
    int local = 0;
    for (int i = s; i < e; ++i) local += cnt[i];
    __shared__ int sm[SCAN_THREADS];
    sm[t] = local;
    __syncthreads();
    for (int o = SCAN_THREADS / 2; o > 0; o >>= 1) {
        if (t < o) sm[t] += sm[t + o];
        __syncthreads();
    }
    if (t == 0) bsum[b] = sm[0];
}

// single block of SCAN_NB threads: exclusive scan of block sums; writes total
// to off_end (= &cnt[n]).
__global__ __launch_bounds__(SCAN_NB) void scan_block_offsets(
    const int* __restrict__ bsum, int* __restrict__ boff,
    int* __restrict__ off_end)
{
    int t = threadIdx.x;
    __shared__ int sm[SCAN_NB];
    int v = bsum[t];
    sm[t] = v;
    __syncthreads();
    for (int o = 1; o < SCAN_NB; o <<= 1) {
        int x = (t >= o) ? sm[t - o] : 0;
        __syncthreads();
        sm[t] += x;
        __syncthreads();
    }
    boff[t] = sm[t] - v;          // exclusive
    if (t == SCAN_NB - 1) *off_end = sm[SCAN_NB - 1];
}

__global__ __launch_bounds__(SCAN_THREADS) void scan_local(
    int* __restrict__ cnt, int* __restrict__ cur,
    const int* __restrict__ boff, int n, int chunk)
{
    int b = blockIdx.x, t = threadIdx.x;
    int base = b * chunk;
    int end  = base + chunk < n ? base + chunk : n;
    int tch  = (chunk + SCAN_THREADS - 1) / SCAN_THREADS;
    int s = base + t * tch;
    int e = s + tch < end ? s + tch : end;
    int local = 0;
    for (int i = s; i < e; ++i) local += cnt[i];
    __shared__ int sm[SCAN_THREADS];
    sm[t] = local;
    __syncthreads();
    for (int o = 1; o < SCAN_THREADS; o <<= 1) {
        int x = (t >= o) ? sm[t - o] : 0;
        __syncthreads();
        sm[t] += x;
        __syncthreads();
    }
    int run = boff[b] + ((t == 0) ? 0 : sm[t - 1]);
    for (int i = s; i < e; ++i) {
        int c = cnt[i];
        cnt[i] = run;
        cur[i] = run;
        run += c;
    }
}

// Placement: 4 separate 4B scattered stores per edge (empirically ~2x faster
// than packed int2 8B stores on gfx950 — round-3 regression evidence).
__global__ __launch_bounds__(256) void edge_place(
    const int* __restrict__ u_idx, const int* __restrict__ i_idx,
    const float* __restrict__ edge_norm,
    int* __restrict__ cur, int n_i,
    int* __restrict__ src, float* __restrict__ w,
    int su_shift, int si_shift)
{
    int e = blockIdx.x * blockDim.x + threadIdx.x;
    if (e >= NUM_EDGES) return;
    int u = u_idx[e];
    int i = i_idx[e];
    float wt = edge_norm[e];
    int pi = atomicAdd(&cur[(u >> su_shift) * NUM_ITEMS + i], 1);
    src[pi] = u;  w[pi] = wt;
    int pu = atomicAdd(&cur[n_i + (i >> si_shift) * NUM_USERS + u], 1);
    src[pu] = i;  w[pu] = wt;
}

// ---------------- gather pass: one 64-lane wave per dst row, one src slice --
__global__ __launch_bounds__(256) void gather_pass(
    const int* __restrict__ off, int bin_base,
    const int* __restrict__ src, const float* __restrict__ w,
    const ushort* __restrict__ emb16,
    float* __restrict__ out, int nrows, int accumulate)
{
    int gid  = blockIdx.x * blockDim.x + threadIdx.x;
    int row  = gid >> 6;
    int lane = gid & 63;
    if (row >= nrows) return;
    int b = bin_base + row;
    int s = off[b];
    int e = off[b + 1];
    float acc = accumulate ? out[(size_t)row * DIM + lane] : 0.f;
    int k = s;
    for (; k + 8 <= e; k += 8) {
        int   s0 = src[k],   s1 = src[k+1], s2 = src[k+2], s3 = src[k+3];
        int   s4 = src[k+4], s5 = src[k+5], s6 = src[k+6], s7 = src[k+7];
        float w0 = w[k],   w1 = w[k+1], w2 = w[k+2], w3 = w[k+3];
        float w4 = w[k+4], w5 = w[k+5], w6 = w[k+6], w7 = w[k+7];
        ushort b0 = emb16[(size_t)s0 * DIM + lane];
        ushort b1 = emb16[(size_t)s1 * DIM + lane];
        ushort b2 = emb16[(size_t)s2 * DIM + lane];
        ushort b3 = emb16[(size_t)s3 * DIM + lane];
        ushort b4 = emb16[(size_t)s4 * DIM + lane];
        ushort b5 = emb16[(size_t)s5 * DIM + lane];
        ushort b6 = emb16[(size_t)s6 * DIM + lane];
        ushort b7 = emb16[(size_t)s7 * DIM + lane];
        acc += w0 * __uint_as_float((uint)b0 << 16);
        acc += w1 * __uint_as_float((uint)b1 << 16);
        acc += w2 * __uint_as_float((uint)b2 << 16);
        acc += w3 * __uint_as_float((uint)b3 << 16);
        acc += w4 * __uint_as_float((uint)b4 << 16);
        acc += w5 * __uint_as_float((uint)b5 << 16);
        acc += w6 * __uint_as_float((uint)b6 << 16);
        acc += w7 * __uint_as_float((uint)b7 << 16);
    }
    for (; k + 4 <= e; k += 4) {
        int   s0 = src[k],   s1 = src[k+1], s2 = src[k+2], s3 = src[k+3];
        float w0 = w[k],   w1 = w[k+1], w2 = w[k+2], w3 = w[k+3];
        ushort b0 = emb16[(size_t)s0 * DIM + lane];
        ushort b1 = emb16[(size_t)s1 * DIM + lane];
        ushort b2 = emb16[(size_t)s2 * DIM + lane];
        ushort b3 = emb16[(size_t)s3 * DIM + lane];
        acc += w0 * __uint_as_float((uint)b0 << 16);
        acc += w1 * __uint_as_float((uint)b1 << 16);
        acc += w2 * __uint_as_float((uint)b2 << 16);
        acc += w3 * __uint_as_float((uint)b3 << 16);
    }
    for (; k < e; ++k) {
        ushort b0 = emb16[(size_t)src[k] * DIM + lane];
        acc += w[k] * __uint_as_float((uint)b0 << 16);
    }
    out[(size_t)row * DIM + lane] = acc;
}

extern "C" void kernel_launch(void* const* d_in, const int* in_sizes, int n_in,
                              void* d_out, int out_size, void* d_ws, size_t ws_size,
                              hipStream_t stream) {
    const float* user_emb  = (const float*)d_in[0];
    const float* item_emb  = (const float*)d_in[1];
    const float* edge_norm = (const float*)d_in[2];
    const int*   u_idx     = (const int*)d_in[3];
    const int*   i_idx     = (const int*)d_in[4];

    float* agg_users = (float*)d_out;                        // 100000*64
    float* agg_items = agg_users + (size_t)NUM_USERS * DIM;  // 50000*64

    const size_t csr_bytes  = (size_t)NUM_EDGES * 2 * (sizeof(int) + sizeof(float));
    const size_t bf16_bytes = ((size_t)NUM_USERS + NUM_ITEMS) * DIM * sizeof(ushort);
    auto need_for = [&](int SU, int SI) -> size_t {
        size_t n_total = (size_t)SU * NUM_ITEMS + (size_t)SI * NUM_USERS;
        size_t off_bytes = (2 * n_total + 1 + 2 * SCAN_NB) * sizeof(int);
        return off_bytes + 64 + csr_bytes + 64 + bf16_bytes;
    };

    int SU, SI, su_shift, si_shift;
    if (ws_size >= need_for(SLICES_U, SLICES_I)) {
        SU = SLICES_U; SI = SLICES_I;
        su_shift = SLICE_SHIFT; si_shift = SLICE_SHIFT;
    } else if (ws_size >= need_for(1, 1)) {
        SU = 1; SI = 1;
        su_shift = 17; si_shift = 17;   // 2^17 > both table sizes -> slice 0
    } else {
        hipMemsetAsync(d_out, 0, (size_t)out_size * sizeof(float), stream);
        const long long total_threads = (long long)NUM_EDGES * 64;
        const int blocks = (int)((total_threads + 255) / 256);
        lightgcn_scatter<<<blocks, 256, 0, stream>>>(
            user_emb, item_emb, edge_norm, u_idx, i_idx, agg_users, agg_items);
        return;
    }

    const int n_i = SU * NUM_ITEMS;
    const int n_u = SI * NUM_USERS;
    const int n_total = n_i + n_u;

    char* p = (char*)d_ws;
    int*   cnt  = (int*)p;   p += (size_t)(n_total + 1) * sizeof(int);
    int*   cur  = (int*)p;   p += (size_t)n_total * sizeof(int);
    int*   bsum = (int*)p;   p += (size_t)SCAN_NB * sizeof(int);
    int*   boff = (int*)p;   p += (size_t)SCAN_NB * sizeof(int);
    p = (char*)(((uintptr_t)p + 63) & ~(uintptr_t)63);
    int*   src  = (int*)p;   p += (size_t)2 * NUM_EDGES * sizeof(int);
    float* w    = (float*)p; p += (size_t)2 * NUM_EDGES * sizeof(float);
    p = (char*)(((uintptr_t)p + 63) & ~(uintptr_t)63);
    ushort* ue16 = (ushort*)p; p += (size_t)NUM_USERS * DIM * sizeof(ushort);
    ushort* ie16 = (ushort*)p;

    // zero the histogram bins (cur is fully written by scan_local)
    hipMemsetAsync(cnt, 0, (size_t)(n_total + 1) * sizeof(int), stream);

    const int un4 = NUM_USERS * DIM / 4;
    const int in4 = NUM_ITEMS * DIM / 4;
    convert_bf16<<<(un4 + 255) / 256, 256, 0, stream>>>(
        (const float4*)user_emb, ue16, un4);
    convert_bf16<<<(in4 + 255) / 256, 256, 0, stream>>>(
        (const float4*)item_emb, ie16, in4);

    edge_hist<<<(NUM_EDGES / 4 + 255) / 256, 256, 0, stream>>>(
        (const int4*)u_idx, (const int4*)i_idx, cnt, n_i, su_shift, si_shift);

    const int chunk = (n_total + SCAN_NB - 1) / SCAN_NB;
    scan_block_sums<<<SCAN_NB, SCAN_THREADS, 0, stream>>>(cnt, bsum, n_total, chunk);
    scan_block_offsets<<<1, SCAN_NB, 0, stream>>>(bsum, boff, cnt + n_total);
    scan_local<<<SCAN_NB, SCAN_THREADS, 0, stream>>>(cnt, cur, boff, n_total, chunk);

    edge_place<<<(NUM_EDGES + 255) / 256, 256, 0, stream>>>(
        u_idx, i_idx, edge_norm, cur, n_i, src, w, su_shift, si_shift);

    // agg_items: gather user rows, one launch per user-table slice
    for (int s = 0; s < SU; ++s) {
        gather_pass<<<((NUM_ITEMS * 64) + 255) / 256, 256, 0, stream>>>(
            cnt, s * NUM_ITEMS, src, w, ue16, agg_items, NUM_ITEMS, s > 0 ? 1 : 0);
    }
    // agg_users: gather item rows, one launch per item-table slice
    for (int s = 0; s < SI; ++s) {
        gather_pass<<<((NUM_USERS * 64) + 255) / 256, 256, 0, stream>>>(
            cnt, n_i + s * NUM_USERS, src, w, ie16, agg_users, NUM_USERS,
            s > 0 ? 1 : 0);
    }
}